// Round 8
// baseline (284.542 us; speedup 1.0000x reference)
//
#include <hip/hip_runtime.h>
#include <hip/hip_bf16.h>

#define E_TOT 50000
#define NF    64
#define B_TOT 64
#define B_TILE 16
#define BLOCK  256
#define E_PB   16              // e's per block (256 threads / 16 lanes per e)
#define LOG2E  1.4426950408889634f
// grid = (E_TOT/E_PB, B_TOT/B_TILE) = (3125, 4) -- exact, no tail

// out[b,e] = sum_f exp(-(HL[b,f] - NL[e,f] - c[f])^2 / var[f]) * W[b,f]
// q[f]=sqrt(log2e/var[f]); A[b,f]=(HL-c)*q; n=NL*q; phi=exp2(-(A-n)^2)
//
// R8: f-on-lane. Lane l -> e = e0 + (l>>4), owns f = 4*(l&15)..+3.
//  - ONE global_load_dwordx4 per thread covers all its NL needs; per wave
//    that's 1KB fully contiguous (kills R2's 64-line splatter per load).
//  - A/W via LDS multicast (16 distinct addrs/wave, 2-way aliasing = free).
//  - f-sum: 4-step __shfl_xor butterfly within 16-lane groups (~3% overhead).
//  - Stores staged in LDS so each 16-lane store = one full 64B line.
__global__ __launch_bounds__(BLOCK, 8)
void kbln_kernel(const float* __restrict__ NL,       // [E, F]
                 const float* __restrict__ c,        // [F]
                 const float* __restrict__ varr,     // [F]
                 const float* __restrict__ NFW,      // [R, F]
                 const int*   __restrict__ head_ids, // [B]
                 const int*   __restrict__ rel_ids,  // [B]
                 float*       __restrict__ out)      // [B, E]
{
    __shared__ float sQ[NF];
    __shared__ float sA[B_TILE][NF];
    __shared__ float sW[B_TILE][NF];
    __shared__ float sOut[B_TILE][E_PB];

    const int tid = threadIdx.x;
    const int b0  = blockIdx.y * B_TILE;
    const int el  = tid >> 4;        // 0..15: which e in the block
    const int ch  = tid & 15;        // f-chunk: f = 4*ch .. 4*ch+3
    const int e   = blockIdx.x * E_PB + el;   // always < 50000

    if (tid < NF) sQ[tid] = sqrtf(LOG2E / varr[tid]);
    __syncthreads();

    // Stage A (folded head literals) and W for this block's 16 b's.
    for (int s = tid; s < B_TILE * NF; s += BLOCK) {
        const int bi = s >> 6;
        const int f  = s & (NF - 1);
        const int h  = head_ids[b0 + bi];
        const int r  = rel_ids[b0 + bi];
        sA[bi][f] = (NL[(size_t)h * NF + f] - c[f]) * sQ[f];
        sW[bi][f] = NFW[(size_t)r * NF + f];
    }
    __syncthreads();

    // This thread's 4 features of NL row e, pre-scaled by q.
    const float4 v = *reinterpret_cast<const float4*>(NL + (size_t)e * NF + 4 * ch);
    const float4 q = *reinterpret_cast<const float4*>(&sQ[4 * ch]);
    float4 n;
    n.x = v.x * q.x; n.y = v.y * q.y; n.z = v.z * q.z; n.w = v.w * q.w;

    float acc[B_TILE];
#pragma unroll
    for (int bi = 0; bi < B_TILE; ++bi) {
        const float4 a = *reinterpret_cast<const float4*>(&sA[bi][4 * ch]);
        const float4 w = *reinterpret_cast<const float4*>(&sW[bi][4 * ch]);
        float t, s;
        t = a.x - n.x; s  = __builtin_amdgcn_exp2f(t * -t) * w.x;
        t = a.y - n.y; s  = fmaf(__builtin_amdgcn_exp2f(t * -t), w.y, s);
        t = a.z - n.z; s  = fmaf(__builtin_amdgcn_exp2f(t * -t), w.z, s);
        t = a.w - n.w; s  = fmaf(__builtin_amdgcn_exp2f(t * -t), w.w, s);
        acc[bi] = s;
    }

    // Reduce over f: butterfly within each 16-lane group (xor masks < 16).
#pragma unroll
    for (int bi = 0; bi < B_TILE; ++bi) {
        float s = acc[bi];
        s += __shfl_xor(s, 1);
        s += __shfl_xor(s, 2);
        s += __shfl_xor(s, 4);
        s += __shfl_xor(s, 8);
        if (ch == 0) sOut[bi][el] = s;
    }
    __syncthreads();

    // Store phase: 256 threads write 256 floats; per bi, 16 lanes cover
    // exactly one 64B line of out (row start and e0 both 64B-aligned).
    {
        const int bi = tid >> 4;
        const int j  = tid & 15;
        out[(size_t)(b0 + bi) * E_TOT + blockIdx.x * E_PB + j] = sOut[bi][j];
    }
}

extern "C" void kernel_launch(void* const* d_in, const int* in_sizes, int n_in,
                              void* d_out, int out_size, void* d_ws, size_t ws_size,
                              hipStream_t stream)
{
    const float* NL       = (const float*)d_in[0];
    const float* c        = (const float*)d_in[1];
    const float* varr     = (const float*)d_in[2];
    const float* NFW      = (const float*)d_in[3];
    const int*   head_ids = (const int*)d_in[4];
    const int*   rel_ids  = (const int*)d_in[5];
    float*       out      = (float*)d_out;

    dim3 grid(E_TOT / E_PB, B_TOT / B_TILE);   // (3125, 4), exact
    kbln_kernel<<<grid, dim3(BLOCK), 0, stream>>>(NL, c, varr, NFW,
                                                  head_ids, rel_ids, out);
}

// Round 9
// 48.437 us; speedup vs baseline: 5.8745x; 5.8745x over previous
//
#include <hip/hip_runtime.h>
#include <hip/hip_bf16.h>

#define E_TOT 50000
#define NF    64
#define B_TOT 64
#define B_TILE 8
#define E_PT   2
#define BLOCK  256
#define EPB   (BLOCK * E_PT)   // 512 e's per block
#define LOG2E 1.4426950408889634f

// out[b,e] = sum_f exp(-(HL[b,f] - NL[e,f] - c[f])^2 / var[f]) * W[b,f]
// q[f]=sqrt(log2e/var[f]); A[b,f]=(HL-c)*q; n=NL*q; phi=exp2(-(A-n)^2)
//
// R9 = R2 (best clean kernel, 40.8us, LDS-pipe-bound) + E_PT=2:
// each broadcast ds_read_b128 of A/W now serves 2 e's per lane -> DS work
// halves (31us -> 15.5us per CU), below the trans+VALU issue floor.
// Spill discipline (R6/R7/R8 post-mortem): launch_bounds(256,4) = 128-VGPR
// cap, ~60 live -> no scratch. unroll 4 bounds load hoisting.
__global__ __launch_bounds__(BLOCK, 4)
void kbln_kernel(const float* __restrict__ NL,       // [E, F]
                 const float* __restrict__ c,        // [F]
                 const float* __restrict__ varr,     // [F]
                 const float* __restrict__ NFW,      // [R, F]
                 const int*   __restrict__ head_ids, // [B]
                 const int*   __restrict__ rel_ids,  // [B]
                 float*       __restrict__ out)      // [B, E]
{
    __shared__ float sQ[NF];
    __shared__ float4 sA[B_TILE][NF / 4];
    __shared__ float4 sW[B_TILE][NF / 4];

    const int tid = threadIdx.x;
    const int b0  = blockIdx.y * B_TILE;

    if (tid < NF) sQ[tid] = sqrtf(LOG2E / varr[tid]);
    __syncthreads();

    // Stage folded head literals A and weights W for this block's 8 b's.
    for (int s = tid; s < B_TILE * NF; s += BLOCK) {
        const int bi = s >> 6;
        const int f  = s & (NF - 1);
        const int h  = head_ids[b0 + bi];
        const int r  = rel_ids[b0 + bi];
        reinterpret_cast<float*>(&sA[bi][0])[f] =
            (NL[(size_t)h * NF + f] - c[f]) * sQ[f];
        reinterpret_cast<float*>(&sW[bi][0])[f] = NFW[(size_t)r * NF + f];
    }
    __syncthreads();

    // Two e's per thread, BLOCK apart (keeps every load coalesced).
    const int e0  = blockIdx.x * EPB + tid;          // max 49919 < E_TOT
    const int e1  = e0 + BLOCK;
    const bool ok1 = (e1 < E_TOT);
    const int e1c = ok1 ? e1 : (E_TOT - 1);          // clamp tail loads

    const float4* nlA = reinterpret_cast<const float4*>(NL + (size_t)e0  * NF);
    const float4* nlB = reinterpret_cast<const float4*>(NL + (size_t)e1c * NF);
    const float4* q4  = reinterpret_cast<const float4*>(sQ);

    float acc0[B_TILE], acc1[B_TILE];
#pragma unroll
    for (int bi = 0; bi < B_TILE; ++bi) { acc0[bi] = 0.f; acc1[bi] = 0.f; }

#pragma unroll 4
    for (int i = 0; i < NF / 4; ++i) {
        const float4 q  = q4[i];
        const float4 va = nlA[i];
        const float4 vb = nlB[i];
        float4 na, nb;
        na.x = va.x * q.x; na.y = va.y * q.y; na.z = va.z * q.z; na.w = va.w * q.w;
        nb.x = vb.x * q.x; nb.y = vb.y * q.y; nb.z = vb.z * q.z; nb.w = vb.w * q.w;
#pragma unroll
        for (int bi = 0; bi < B_TILE; ++bi) {
            const float4 a = sA[bi][i];   // broadcast ds_read_b128, serves 2 e's
            const float4 w = sW[bi][i];
            float t;
            t = a.x - na.x; acc0[bi] = fmaf(__builtin_amdgcn_exp2f(-(t * t)), w.x, acc0[bi]);
            t = a.x - nb.x; acc1[bi] = fmaf(__builtin_amdgcn_exp2f(-(t * t)), w.x, acc1[bi]);
            t = a.y - na.y; acc0[bi] = fmaf(__builtin_amdgcn_exp2f(-(t * t)), w.y, acc0[bi]);
            t = a.y - nb.y; acc1[bi] = fmaf(__builtin_amdgcn_exp2f(-(t * t)), w.y, acc1[bi]);
            t = a.z - na.z; acc0[bi] = fmaf(__builtin_amdgcn_exp2f(-(t * t)), w.z, acc0[bi]);
            t = a.z - nb.z; acc1[bi] = fmaf(__builtin_amdgcn_exp2f(-(t * t)), w.z, acc1[bi]);
            t = a.w - na.w; acc0[bi] = fmaf(__builtin_amdgcn_exp2f(-(t * t)), w.w, acc0[bi]);
            t = a.w - nb.w; acc1[bi] = fmaf(__builtin_amdgcn_exp2f(-(t * t)), w.w, acc1[bi]);
        }
    }

#pragma unroll
    for (int bi = 0; bi < B_TILE; ++bi) {
        out[(size_t)(b0 + bi) * E_TOT + e0] = acc0[bi];
        if (ok1) out[(size_t)(b0 + bi) * E_TOT + e1] = acc1[bi];
    }
}

extern "C" void kernel_launch(void* const* d_in, const int* in_sizes, int n_in,
                              void* d_out, int out_size, void* d_ws, size_t ws_size,
                              hipStream_t stream)
{
    const float* NL       = (const float*)d_in[0];
    const float* c        = (const float*)d_in[1];
    const float* varr     = (const float*)d_in[2];
    const float* NFW      = (const float*)d_in[3];
    const int*   head_ids = (const int*)d_in[4];
    const int*   rel_ids  = (const int*)d_in[5];
    float*       out      = (float*)d_out;

    dim3 grid((E_TOT + EPB - 1) / EPB, B_TOT / B_TILE);   // (98, 8)
    kbln_kernel<<<grid, dim3(BLOCK), 0, stream>>>(NL, c, varr, NFW,
                                                  head_ids, rel_ids, out);
}

// Round 10
// 44.850 us; speedup vs baseline: 6.3443x; 1.0800x over previous
//
#include <hip/hip_runtime.h>
#include <hip/hip_bf16.h>

#define E_TOT 50000
#define NF    64
#define B_TOT 64
#define B_TILE 8
#define BLOCK  64
#define LOG2E 1.4426950408889634f

// out[b,e] = sum_f exp(-(HL[b,f] - NL[e,f] - c[f])^2 / var[f]) * W[b,f]
// q[f]=sqrt(log2e/var[f]); A[b,f]=(HL-c)*q; n=NL*q; phi=exp2(-(A-n)^2)
//
// R10 = R2 structure (best clean kernel: thread=e, LDS-broadcast A/W,
// 8 acc chains) with BLOCK=64: grid (782,8)=6256 one-wave blocks
// -> ~24 resident waves/CU (vs 12) to hide the NL-load latency that R9
// exposed. Barriers are intra-wave (~free). No layout change -> no spill
// (VGPR ~52 < 85 cap), no write-amp.
__global__ __launch_bounds__(BLOCK, 6)
void kbln_kernel(const float* __restrict__ NL,       // [E, F]
                 const float* __restrict__ c,        // [F]
                 const float* __restrict__ varr,     // [F]
                 const float* __restrict__ NFW,      // [R, F]
                 const int*   __restrict__ head_ids, // [B]
                 const int*   __restrict__ rel_ids,  // [B]
                 float*       __restrict__ out)      // [B, E]
{
    __shared__ float sQ[NF];
    __shared__ float4 sA[B_TILE][NF / 4];
    __shared__ float4 sW[B_TILE][NF / 4];

    const int tid = threadIdx.x;
    const int b0  = blockIdx.y * B_TILE;
    const int e   = blockIdx.x * BLOCK + tid;

    sQ[tid] = sqrtf(LOG2E / varr[tid]);
    __syncthreads();

    // Stage folded head literals A and weights W for this block's 8 b's.
    for (int s = tid; s < B_TILE * NF; s += BLOCK) {
        const int bi = s >> 6;
        const int f  = s & (NF - 1);
        const int h  = head_ids[b0 + bi];
        const int r  = rel_ids[b0 + bi];
        reinterpret_cast<float*>(&sA[bi][0])[f] =
            (NL[(size_t)h * NF + f] - c[f]) * sQ[f];
        reinterpret_cast<float*>(&sW[bi][0])[f] = NFW[(size_t)r * NF + f];
    }
    __syncthreads();

    if (e >= E_TOT) return;  // no barriers below (tail block only)

    const float4* nl4 = reinterpret_cast<const float4*>(NL + (size_t)e * NF);
    const float4* q4  = reinterpret_cast<const float4*>(sQ);

    float acc[B_TILE];
#pragma unroll
    for (int bi = 0; bi < B_TILE; ++bi) acc[bi] = 0.0f;

#pragma unroll
    for (int i = 0; i < NF / 4; ++i) {
        const float4 v = nl4[i];   // NL row (splatter; hidden by 24 waves/CU)
        const float4 q = q4[i];    // LDS broadcast
        float4 n;
        n.x = v.x * q.x; n.y = v.y * q.y; n.z = v.z * q.z; n.w = v.w * q.w;
#pragma unroll
        for (int bi = 0; bi < B_TILE; ++bi) {
            const float4 a = sA[bi][i];  // broadcast ds_read_b128
            const float4 w = sW[bi][i];
            float t;
            t = a.x - n.x; acc[bi] = fmaf(__builtin_amdgcn_exp2f(-(t * t)), w.x, acc[bi]);
            t = a.y - n.y; acc[bi] = fmaf(__builtin_amdgcn_exp2f(-(t * t)), w.y, acc[bi]);
            t = a.z - n.z; acc[bi] = fmaf(__builtin_amdgcn_exp2f(-(t * t)), w.z, acc[bi]);
            t = a.w - n.w; acc[bi] = fmaf(__builtin_amdgcn_exp2f(-(t * t)), w.w, acc[bi]);
        }
    }

#pragma unroll
    for (int bi = 0; bi < B_TILE; ++bi) {
        out[(size_t)(b0 + bi) * E_TOT + e] = acc[bi];
    }
}

extern "C" void kernel_launch(void* const* d_in, const int* in_sizes, int n_in,
                              void* d_out, int out_size, void* d_ws, size_t ws_size,
                              hipStream_t stream)
{
    const float* NL       = (const float*)d_in[0];
    const float* c        = (const float*)d_in[1];
    const float* varr     = (const float*)d_in[2];
    const float* NFW      = (const float*)d_in[3];
    const int*   head_ids = (const int*)d_in[4];
    const int*   rel_ids  = (const int*)d_in[5];
    float*       out      = (float*)d_out;

    dim3 grid((E_TOT + BLOCK - 1) / BLOCK, B_TOT / B_TILE);   // (782, 8)
    kbln_kernel<<<grid, dim3(BLOCK), 0, stream>>>(NL, c, varr, NFW,
                                                  head_ids, rel_ids, out);
}